// Round 1
// baseline (312.464 us; speedup 1.0000x reference)
//
#include <hip/hip_runtime.h>
#include <math.h>

#define Nq 2048
#define Bq 8
#define Kq 4
#define BKq 32
#define TPB 256
#define EPT 8
#define TWO_PI_D 6.283185307179586
#define PI_D 3.141592653589793

// ---------------- helpers ----------------

__device__ __forceinline__ double blk_reduce(double v, double* sh) {
#pragma unroll
  for (int off = 32; off > 0; off >>= 1) v += __shfl_down(v, off, 64);
  int wid = threadIdx.x >> 6;
  int lane = threadIdx.x & 63;
  __syncthreads();
  if (lane == 0) sh[wid] = v;
  __syncthreads();
  double r = sh[0] + sh[1] + sh[2] + sh[3];
  __syncthreads();
  return r;
}

// pentadiagonal opedoub = oper^T @ oper (oper = 2nd-diff w/ -1 endpoints)
__device__ __forceinline__ double pent_mv(const double* __restrict__ p, int i) {
  double acc = ((i == 0 || i == Nq - 1) ? 2.0 : 6.0) * p[i];
  if (i >= 1) acc += ((i == 1 || i == Nq - 1) ? -3.0 : -4.0) * p[i - 1];
  if (i >= 2) acc += p[i - 2];
  if (i <= Nq - 2) acc += ((i == 0 || i == Nq - 2) ? -3.0 : -4.0) * p[i + 1];
  if (i <= Nq - 3) acc += p[i + 2];
  return acc;
}

// CG on (coef*opedoub + diag(diagv)+1e-6 I) x = rhs.
// In: x = x0, r = rhs. Out: x = solution. Element i = tid + e*TPB.
__device__ void cg_block(double coef, const double* diagv, double* r, double* x,
                         double* sh_p, double* sh_red) {
  const int tid = threadIdx.x;
  double pe[EPT];
#pragma unroll
  for (int e = 0; e < EPT; ++e) sh_p[tid + e * TPB] = x[e];
  __syncthreads();
  double rs_loc = 0.0;
#pragma unroll
  for (int e = 0; e < EPT; ++e) {
    int i = tid + e * TPB;
    double Ap = coef * pent_mv(sh_p, i) + (diagv[e] + 1e-6) * sh_p[i];
    r[e] -= Ap;
    rs_loc += r[e] * r[e];
  }
  double rsold = blk_reduce(rs_loc, sh_red);
  __syncthreads();  // all pent_mv reads done before overwrite
#pragma unroll
  for (int e = 0; e < EPT; ++e) { pe[e] = r[e]; sh_p[tid + e * TPB] = r[e]; }
  __syncthreads();
  for (int it = 0; it < 30; ++it) {
    double Ap[EPT];
    double pap_loc = 0.0;
#pragma unroll
    for (int e = 0; e < EPT; ++e) {
      int i = tid + e * TPB;
      Ap[e] = coef * pent_mv(sh_p, i) + (diagv[e] + 1e-6) * pe[e];
      pap_loc += pe[e] * Ap[e];
    }
    double pAp = blk_reduce(pap_loc, sh_red);
    double a = rsold / (pAp + 1e-12);
    double rs2 = 0.0;
#pragma unroll
    for (int e = 0; e < EPT; ++e) {
      x[e] += a * pe[e];
      r[e] -= a * Ap[e];
      rs2 += r[e] * r[e];
    }
    double rsnew = blk_reduce(rs2, sh_red);
    if (sqrt(rsnew) < 1e-6) break;  // == reference freeze-on-done
    double bta = rsnew / (rsold + 1e-12);
#pragma unroll
    for (int e = 0; e < EPT; ++e) pe[e] = r[e] + bta * pe[e];
    // blk_reduce trailing barrier guarantees all reads of sh_p finished
#pragma unroll
    for (int e = 0; e < EPT; ++e) sh_p[tid + e * TPB] = pe[e];
    __syncthreads();
    rsold = rsnew;
  }
}

// ---------------- kernel A: hyperparameter MLP ----------------
__global__ __launch_bounds__(64) void hyper_kernel(
    const float* __restrict__ init_freqs, const float* __restrict__ alpha_p,
    const float* __restrict__ beta_p, const int* __restrict__ iter_p,
    const float* __restrict__ fe_w1, const float* __restrict__ fe_b1,
    const float* __restrict__ fe_w2, const float* __restrict__ fe_b2,
    const float* __restrict__ pr_w1, const float* __restrict__ pr_b1,
    const float* __restrict__ pr_w2, const float* __restrict__ pr_b2,
    const float* __restrict__ pr_w3, const float* __restrict__ pr_b3,
    const float* __restrict__ iter_w_p, double* __restrict__ hdr,
    float* __restrict__ out_scal) {
  int tid = threadIdx.x;
  double alpha = (double)alpha_p[0], beta = (double)beta_p[0];
  double iter = (double)iter_p[0];
  double res0 = 0.0, res1 = 0.0;
  if (tid < Bq) {
    int b = tid;
    double avg = 0.0;
    for (int k = 0; k < Kq; ++k) avg += (double)init_freqs[b * Kq + k];
    avg *= (1.0 / Kq);
    double h1[32];
    for (int j = 0; j < 32; ++j) {
      double v = (double)fe_w1[j] * avg + (double)fe_b1[j];
      h1[j] = v > 0.0 ? v : 0.0;
    }
    double z[18];
    for (int j = 0; j < 16; ++j) {
      double acc = (double)fe_b2[j];
      for (int i = 0; i < 32; ++i) acc += (double)fe_w2[j * 32 + i] * h1[i];
      z[j] = acc > 0.0 ? acc : 0.0;
    }
    z[16] = alpha;
    z[17] = beta;
    double z1[64];
    for (int j = 0; j < 64; ++j) {
      double acc = (double)pr_b1[j];
      for (int i = 0; i < 18; ++i) acc += (double)pr_w1[j * 18 + i] * z[i];
      z1[j] = acc > 0.0 ? acc : 0.0;
    }
    double z2[32];
    for (int j = 0; j < 32; ++j) {
      double acc = (double)pr_b2[j];
      for (int i = 0; i < 64; ++i) acc += (double)pr_w2[j * 64 + i] * z1[i];
      z2[j] = acc > 0.0 ? acc : 0.0;
    }
    double fac = 1.0 / (1.0 + exp(-(double)iter_w_p[0] * iter));
    double rr[2];
    for (int c = 0; c < 2; ++c) {
      double acc = (double)pr_b3[c];
      for (int i = 0; i < 32; ++i) acc += (double)pr_w3[c * 32 + i] * z2[i];
      rr[c] = tanh(acc) * fac * 0.1;
    }
    res0 = rr[0] * alpha;
    res1 = rr[1] * beta;
  }
#pragma unroll
  for (int off = 4; off > 0; off >>= 1) {
    res0 += __shfl_down(res0, off, 64);
    res1 += __shfl_down(res1, off, 64);
  }
  if (tid == 0) {
    double na = alpha + res0 / (double)Bq;
    na = fmin(fmax(na, 1e-6), 0.01);
    double nb = beta + res1 / (double)Bq;
    nb = fmin(fmax(nb, 1e-6), 0.1);
    double betathr = fmin(pow(10.0, iter / 36.0 - 10.0), nb);
    hdr[0] = na;
    hdr[1] = nb;
    hdr[2] = 2.0 / na;       // coefA
    hdr[3] = 2.0 / betathr;  // coefS
    hdr[4] = 1.0 / na;       // inv_alpha
    out_scal[0] = (float)na;
    out_scal[1] = (float)nb;
  }
}

// ---------------- kernel B: u = projec5(...) ----------------
__global__ __launch_bounds__(TPB) void u_kernel(
    const float* __restrict__ s, const float* __restrict__ sum_x,
    const float* __restrict__ sum_y, const float* __restrict__ lamuda,
    const float* __restrict__ var_p, const double* __restrict__ hdr,
    double* __restrict__ u_w) {
  __shared__ double sh_red[4];
  __shared__ double sh_scale;
  int bb = blockIdx.x * Nq;
  int tid = threadIdx.x;
  double inva = hdr[4];
  double t[EPT];
  double loc = 0.0;
#pragma unroll
  for (int e = 0; e < EPT; ++e) {
    int i = tid + e * TPB;
    t[e] = (double)s[bb + i] - (double)sum_x[bb + i] - (double)sum_y[bb + i] -
           (double)lamuda[bb + i] * inva;
    loc += t[e] * t[e];
  }
  double nsq = blk_reduce(loc, sh_red);
  if (tid == 0) {
    double n = sqrt(nsq);
    double ee = sqrt((double)Nq * (double)var_p[0]);
    sh_scale = (n > ee) ? ee / fmax(n, 1e-30) : 1.0;
  }
  __syncthreads();
  double scale = sh_scale;
#pragma unroll
  for (int e = 0; e < EPT; ++e) u_w[bb + tid + e * TPB] = t[e] * scale;
}

// ---------------- kernel C: cumtrapz scan + rhs ----------------
__global__ __launch_bounds__(TPB) void phase_rhs_kernel(
    const float* __restrict__ s, const float* __restrict__ eIF,
    const float* __restrict__ xm, const float* __restrict__ ym,
    const float* __restrict__ sum_x, const float* __restrict__ sum_y,
    const float* __restrict__ lamuda, const float* __restrict__ fs_p,
    const double* __restrict__ hdr, const double* __restrict__ u_w,
    double* __restrict__ cos_w, double* __restrict__ sin_w,
    double* __restrict__ rhsx_w, double* __restrict__ rhsy_w) {
  __shared__ double sh[TPB];
  __shared__ double sh_y0;
  int row = blockIdx.x;
  int bb = (row >> 2) * Nq;  // K=4
  int base = row * Nq;
  int tid = threadIdx.x;
  int i0 = tid * EPT;
  double e[EPT], l[EPT];
#pragma unroll
  for (int j = 0; j < EPT; ++j) e[j] = (double)eIF[base + i0 + j];
  l[0] = e[0];
#pragma unroll
  for (int j = 1; j < EPT; ++j) l[j] = l[j - 1] + e[j];
  if (tid == 0) sh_y0 = e[0];
  sh[tid] = l[EPT - 1];
  __syncthreads();
  for (int off = 1; off < TPB; off <<= 1) {
    double t = (tid >= off) ? sh[tid - off] : 0.0;
    __syncthreads();
    if (tid >= off) sh[tid] += t;
    __syncthreads();
  }
  double offs = sh[tid] - l[EPT - 1];  // exclusive prefix
  double y0 = sh_y0;
  double dx = 1.0 / (double)fs_p[0];
  double inva = hdr[4];
  double c0 = PI_D * dx;
#pragma unroll
  for (int j = 0; j < EPT; ++j) {
    int i = i0 + j;
    double S = offs + l[j];
    double ph = c0 * (2.0 * S - e[j] - y0);  // == 2*pi*cumtrapz
    double sv, cv;
    sincos(ph, &sv, &cv);
    double xmv = (double)xm[base + i], ymv = (double)ym[base + i];
    double resid = (double)s[bb + i] - ((double)sum_x[bb + i] - xmv * cv) -
                   ((double)sum_y[bb + i] - ymv * sv) - u_w[bb + i] -
                   (double)lamuda[bb + i] * inva;
    cos_w[base + i] = cv;
    sin_w[base + i] = sv;
    rhsx_w[base + i] = cv * resid;
    rhsy_w[base + i] = sv * resid;
  }
}

// ---------------- kernel D: CG for xs (blocks 0..31) and ys (32..63) ----------
__global__ __launch_bounds__(TPB) void cg_xy_kernel(
    const double* __restrict__ cos_w, const double* __restrict__ sin_w,
    const double* __restrict__ rhsx_w, const double* __restrict__ rhsy_w,
    const float* __restrict__ xm, const float* __restrict__ ym,
    const double* __restrict__ hdr, double* __restrict__ xs_w,
    double* __restrict__ ys_w) {
  __shared__ double sh_p[Nq];
  __shared__ double sh_red[4];
  int id = blockIdx.x;
  int base = (id & 31) * Nq;
  bool isY = id >= 32;
  double coef = hdr[2];
  const double* trig = isY ? sin_w : cos_w;
  const double* rh = isY ? rhsy_w : rhsx_w;
  const float* x0f = isY ? ym : xm;
  int tid = threadIdx.x;
  double diagv[EPT], r[EPT], x[EPT];
#pragma unroll
  for (int e = 0; e < EPT; ++e) {
    int i = base + tid + e * TPB;
    double t = trig[i];
    diagv[e] = t * t;
    r[e] = rh[i];
    x[e] = (double)x0f[i];
  }
  cg_block(coef, diagv, r, x, sh_p, sh_red);
  double* outw = isY ? ys_w : xs_w;
#pragma unroll
  for (int e = 0; e < EPT; ++e) outw[base + tid + e * TPB] = x[e];
}

// ---------------- kernel E: deltaIF ----------------
__global__ __launch_bounds__(TPB) void dif_kernel(const double* __restrict__ xs_w,
                                                  const double* __restrict__ ys_w,
                                                  const float* __restrict__ fs_p,
                                                  double* __restrict__ dif_w) {
  int base = blockIdx.x * Nq;
  int tid = threadIdx.x;
  double dx = 1.0 / (double)fs_p[0];
  double invdx = 1.0 / dx, inv2dx = 0.5 / dx;
#pragma unroll
  for (int e = 0; e < EPT; ++e) {
    int i = tid + e * TPB;
    double xv = xs_w[base + i], yv = ys_w[base + i];
    double xbar, ybar;
    if (i == 0) {
      xbar = (xs_w[base + 1] - xs_w[base + 0]) * invdx;
      ybar = (ys_w[base + 1] - ys_w[base + 0]) * invdx;
    } else if (i == Nq - 1) {
      xbar = (xs_w[base + Nq - 1] - xs_w[base + Nq - 2]) * invdx;
      ybar = (ys_w[base + Nq - 1] - ys_w[base + Nq - 2]) * invdx;
    } else {
      xbar = (xs_w[base + i + 1] - xs_w[base + i - 1]) * inv2dx;
      ybar = (ys_w[base + i + 1] - ys_w[base + i - 1]) * inv2dx;
    }
    double denom = xv * xv + yv * yv + 1e-12;
    dif_w[base + i] = (xv * ybar - yv * xbar) / (denom * TWO_PI_D);
  }
}

// ---------------- kernel F: smooth CG + eIF/xm/ym outputs ----------------
__global__ __launch_bounds__(TPB) void cg_smooth_kernel(
    const double* __restrict__ dif_w, const double* __restrict__ hdr,
    const float* __restrict__ eIF, const double* __restrict__ xs_w,
    const double* __restrict__ ys_w, const float* __restrict__ xm,
    const float* __restrict__ ym, const int* __restrict__ mode_mask,
    double* __restrict__ eifn_w, float* __restrict__ out_eIF,
    float* __restrict__ out_xm, float* __restrict__ out_ym) {
  __shared__ double sh_p[Nq];
  __shared__ double sh_red[4];
  int row = blockIdx.x;
  int base = row * Nq;
  int tid = threadIdx.x;
  double coef = hdr[3];
  double diagv[EPT], r[EPT], x[EPT];
#pragma unroll
  for (int e = 0; e < EPT; ++e) {
    diagv[e] = 1.0;
    r[e] = dif_w[base + tid + e * TPB];
    x[e] = 0.0;
  }
  cg_block(coef, diagv, r, x, sh_p, sh_red);
  bool active = mode_mask[row] != 0;
#pragma unroll
  for (int e = 0; e < EPT; ++e) {
    int i = base + tid + e * TPB;
    double eifv = (double)eIF[i];
    double ne = active ? (eifv - 0.5 * x[e]) : eifv;
    eifn_w[i] = ne;
    out_eIF[i] = (float)ne;
    out_xm[i] = active ? (float)xs_w[i] : xm[i];
    out_ym[i] = active ? (float)ys_w[i] : ym[i];
  }
}

// ---------------- kernel G: new_phase scan + masked contributions -----------
__global__ __launch_bounds__(TPB) void phase2_kernel(
    const double* __restrict__ eifn_w, const double* __restrict__ xs_w,
    const double* __restrict__ ys_w, const float* __restrict__ xm,
    const float* __restrict__ ym, const int* __restrict__ mode_mask,
    const float* __restrict__ fs_p, double* __restrict__ cx_w,
    double* __restrict__ cy_w) {
  __shared__ double sh[TPB];
  __shared__ double sh_y0;
  int row = blockIdx.x;
  int base = row * Nq;
  int tid = threadIdx.x;
  int i0 = tid * EPT;
  double e[EPT], l[EPT];
#pragma unroll
  for (int j = 0; j < EPT; ++j) e[j] = eifn_w[base + i0 + j];
  l[0] = e[0];
#pragma unroll
  for (int j = 1; j < EPT; ++j) l[j] = l[j - 1] + e[j];
  if (tid == 0) sh_y0 = e[0];
  sh[tid] = l[EPT - 1];
  __syncthreads();
  for (int off = 1; off < TPB; off <<= 1) {
    double t = (tid >= off) ? sh[tid - off] : 0.0;
    __syncthreads();
    if (tid >= off) sh[tid] += t;
    __syncthreads();
  }
  double offs = sh[tid] - l[EPT - 1];
  double y0 = sh_y0;
  double dx = 1.0 / (double)fs_p[0];
  double c0 = PI_D * dx;
  bool active = mode_mask[row] != 0;
#pragma unroll
  for (int j = 0; j < EPT; ++j) {
    int i = i0 + j;
    double S = offs + l[j];
    double ph = c0 * (2.0 * S - e[j] - y0);
    double sv, cv;
    sincos(ph, &sv, &cv);
    if (active) {
      cx_w[base + i] = xs_w[base + i] * cv;
      cy_w[base + i] = ys_w[base + i] * sv;
    } else {
      cx_w[base + i] = 0.0;
      cy_w[base + i] = 0.0;
    }
  }
}

// ---------------- kernel H: bsx/bsy sums + new lamuda ----------------
__global__ __launch_bounds__(TPB) void final_kernel(
    const float* __restrict__ s, const float* __restrict__ lamuda,
    const double* __restrict__ u_w, const double* __restrict__ cx_w,
    const double* __restrict__ cy_w, const double* __restrict__ hdr,
    float* __restrict__ out_bsx, float* __restrict__ out_bsy,
    float* __restrict__ out_lam) {
  int b = blockIdx.x;
  int bb = b * Nq;
  int tid = threadIdx.x;
  double na = hdr[0];
#pragma unroll
  for (int e = 0; e < EPT; ++e) {
    int i = tid + e * TPB;
    int gi = bb + i;
    double bx = 0.0, by = 0.0;
#pragma unroll
    for (int k = 0; k < Kq; ++k) {
      bx += cx_w[(b * Kq + k) * Nq + i];
      by += cy_w[(b * Kq + k) * Nq + i];
    }
    double nl = (double)lamuda[gi] + na * (u_w[gi] + bx + by - (double)s[gi]);
    out_bsx[gi] = (float)bx;
    out_bsy[gi] = (float)by;
    out_lam[gi] = (float)nl;
  }
}

// ---------------- launcher ----------------
extern "C" void kernel_launch(void* const* d_in, const int* in_sizes, int n_in,
                              void* d_out, int out_size, void* d_ws, size_t ws_size,
                              hipStream_t stream) {
  (void)in_sizes; (void)n_in; (void)out_size; (void)ws_size;
  const float* s = (const float*)d_in[0];
  const float* eIF = (const float*)d_in[1];
  const float* xm = (const float*)d_in[2];
  const float* ym = (const float*)d_in[3];
  const float* sum_x = (const float*)d_in[4];
  const float* sum_y = (const float*)d_in[5];
  const float* lamuda = (const float*)d_in[6];
  const float* init_freqs = (const float*)d_in[7];
  const int* mode_mask = (const int*)d_in[8];
  const float* alpha = (const float*)d_in[9];
  const float* beta = (const float*)d_in[10];
  const float* var = (const float*)d_in[11];
  const float* fs = (const float*)d_in[12];
  const int* iteration = (const int*)d_in[13];
  const float* fe_w1 = (const float*)d_in[14];
  const float* fe_b1 = (const float*)d_in[15];
  const float* fe_w2 = (const float*)d_in[16];
  const float* fe_b2 = (const float*)d_in[17];
  const float* pr_w1 = (const float*)d_in[18];
  const float* pr_b1 = (const float*)d_in[19];
  const float* pr_w2 = (const float*)d_in[20];
  const float* pr_b2 = (const float*)d_in[21];
  const float* pr_w3 = (const float*)d_in[22];
  const float* pr_b3 = (const float*)d_in[23];
  const float* iter_weight = (const float*)d_in[24];

  float* out = (float*)d_out;
  const int BN = Bq * Nq;      // 16384
  const int BKN = BKq * Nq;    // 65536
  float* out_eIF = out;
  float* out_xm = out + BKN;
  float* out_ym = out + 2 * BKN;
  float* out_bsx = out + 3 * BKN;
  float* out_bsy = out + 3 * BKN + BN;
  float* out_lam = out + 3 * BKN + 2 * BN;
  float* out_scal = out + 3 * BKN + 3 * BN;  // [new_alpha, new_beta]

  double* W = (double*)d_ws;
  double* hdr = W;            // 16
  double* u_w = W + 16;       // BN
  double* cos_w = u_w + BN;   // BKN each below
  double* sin_w = cos_w + BKN;
  double* rhsx_w = sin_w + BKN;
  double* rhsy_w = rhsx_w + BKN;
  double* xs_w = rhsy_w + BKN;
  double* ys_w = xs_w + BKN;
  double* dif_w = ys_w + BKN;
  double* eifn_w = dif_w + BKN;
  double* cx_w = eifn_w + BKN;
  double* cy_w = cx_w + BKN;   // total ~5.4 MB

  hyper_kernel<<<1, 64, 0, stream>>>(init_freqs, alpha, beta, iteration, fe_w1,
                                     fe_b1, fe_w2, fe_b2, pr_w1, pr_b1, pr_w2,
                                     pr_b2, pr_w3, pr_b3, iter_weight, hdr,
                                     out_scal);
  u_kernel<<<Bq, TPB, 0, stream>>>(s, sum_x, sum_y, lamuda, var, hdr, u_w);
  phase_rhs_kernel<<<BKq, TPB, 0, stream>>>(s, eIF, xm, ym, sum_x, sum_y, lamuda,
                                            fs, hdr, u_w, cos_w, sin_w, rhsx_w,
                                            rhsy_w);
  cg_xy_kernel<<<2 * BKq, TPB, 0, stream>>>(cos_w, sin_w, rhsx_w, rhsy_w, xm, ym,
                                            hdr, xs_w, ys_w);
  dif_kernel<<<BKq, TPB, 0, stream>>>(xs_w, ys_w, fs, dif_w);
  cg_smooth_kernel<<<BKq, TPB, 0, stream>>>(dif_w, hdr, eIF, xs_w, ys_w, xm, ym,
                                            mode_mask, eifn_w, out_eIF, out_xm,
                                            out_ym);
  phase2_kernel<<<BKq, TPB, 0, stream>>>(eifn_w, xs_w, ys_w, xm, ym, mode_mask,
                                         fs, cx_w, cy_w);
  final_kernel<<<Bq, TPB, 0, stream>>>(s, lamuda, u_w, cx_w, cy_w, hdr, out_bsx,
                                       out_bsy, out_lam);
}

// Round 2
// 255.667 us; speedup vs baseline: 1.2222x; 1.2222x over previous
//
#include <hip/hip_runtime.h>
#include <math.h>

#define Nq 2048
#define Bq 8
#define Kq 4
#define BKq 32
#define TPB 256
#define EPT 8
#define TWO_PI_D 6.283185307179586
#define PI_D 3.141592653589793

// ---------------- helpers ----------------

__device__ __forceinline__ double blk_reduce(double v, double* sh) {
#pragma unroll
  for (int off = 32; off > 0; off >>= 1) v += __shfl_down(v, off, 64);
  int wid = threadIdx.x >> 6;
  int lane = threadIdx.x & 63;
  __syncthreads();
  if (lane == 0) sh[wid] = v;
  __syncthreads();
  double r = sh[0] + sh[1] + sh[2] + sh[3];
  __syncthreads();
  return r;
}

// pentadiagonal opedoub = oper^T @ oper (oper = 2nd-diff w/ -1 endpoints)
__device__ __forceinline__ double pent_mv(const double* __restrict__ p, int i) {
  double acc = ((i == 0 || i == Nq - 1) ? 2.0 : 6.0) * p[i];
  if (i >= 1) acc += ((i == 1 || i == Nq - 1) ? -3.0 : -4.0) * p[i - 1];
  if (i >= 2) acc += p[i - 2];
  if (i <= Nq - 2) acc += ((i == 0 || i == Nq - 2) ? -3.0 : -4.0) * p[i + 1];
  if (i <= Nq - 3) acc += p[i + 2];
  return acc;
}

// CG on (coef*opedoub + diag(diagv)+1e-6 I) x = rhs.
// In: x = x0, r = rhs. Out: x = solution. Element i = tid + e*TPB.
__device__ void cg_block(double coef, const double* diagv, double* r, double* x,
                         double* sh_p, double* sh_red) {
  const int tid = threadIdx.x;
  double pe[EPT];
#pragma unroll
  for (int e = 0; e < EPT; ++e) sh_p[tid + e * TPB] = x[e];
  __syncthreads();
  double rs_loc = 0.0;
#pragma unroll
  for (int e = 0; e < EPT; ++e) {
    int i = tid + e * TPB;
    double Ap = coef * pent_mv(sh_p, i) + (diagv[e] + 1e-6) * sh_p[i];
    r[e] -= Ap;
    rs_loc += r[e] * r[e];
  }
  double rsold = blk_reduce(rs_loc, sh_red);
  __syncthreads();  // all pent_mv reads done before overwrite
#pragma unroll
  for (int e = 0; e < EPT; ++e) { pe[e] = r[e]; sh_p[tid + e * TPB] = r[e]; }
  __syncthreads();
  for (int it = 0; it < 30; ++it) {
    double Ap[EPT];
    double pap_loc = 0.0;
#pragma unroll
    for (int e = 0; e < EPT; ++e) {
      int i = tid + e * TPB;
      Ap[e] = coef * pent_mv(sh_p, i) + (diagv[e] + 1e-6) * pe[e];
      pap_loc += pe[e] * Ap[e];
    }
    double pAp = blk_reduce(pap_loc, sh_red);
    double a = rsold / (pAp + 1e-12);
    double rs2 = 0.0;
#pragma unroll
    for (int e = 0; e < EPT; ++e) {
      x[e] += a * pe[e];
      r[e] -= a * Ap[e];
      rs2 += r[e] * r[e];
    }
    double rsnew = blk_reduce(rs2, sh_red);
    if (sqrt(rsnew) < 1e-6) break;  // == reference freeze-on-done
    double bta = rsnew / (rsold + 1e-12);
#pragma unroll
    for (int e = 0; e < EPT; ++e) pe[e] = r[e] + bta * pe[e];
    // blk_reduce trailing barrier guarantees all reads of sh_p finished
#pragma unroll
    for (int e = 0; e < EPT; ++e) sh_p[tid + e * TPB] = pe[e];
    __syncthreads();
    rsold = rsnew;
  }
}

// ---------------- kernel A: hyperparameter MLP (parallel) ----------------
// 1 block x 512 threads; neuron-per-thread per layer, activations in LDS.
__global__ __launch_bounds__(512) void hyper_kernel(
    const float* __restrict__ init_freqs, const float* __restrict__ alpha_p,
    const float* __restrict__ beta_p, const int* __restrict__ iter_p,
    const float* __restrict__ fe_w1, const float* __restrict__ fe_b1,
    const float* __restrict__ fe_w2, const float* __restrict__ fe_b2,
    const float* __restrict__ pr_w1, const float* __restrict__ pr_b1,
    const float* __restrict__ pr_w2, const float* __restrict__ pr_b2,
    const float* __restrict__ pr_w3, const float* __restrict__ pr_b3,
    const float* __restrict__ iter_w_p, double* __restrict__ hdr,
    float* __restrict__ out_scal) {
  __shared__ double sh_avg[Bq];
  __shared__ double sh_h1[Bq][32];
  __shared__ double sh_z[Bq][18];
  __shared__ double sh_z1[Bq][64];
  __shared__ double sh_z2[Bq][32];
  __shared__ double sh_res[Bq][2];
  int tid = threadIdx.x;
  double alpha = (double)alpha_p[0], beta = (double)beta_p[0];
  double iter = (double)iter_p[0];

  if (tid < Bq) {
    double avg = 0.0;
#pragma unroll
    for (int k = 0; k < Kq; ++k) avg += (double)init_freqs[tid * Kq + k];
    sh_avg[tid] = avg * (1.0 / Kq);
  }
  __syncthreads();
  if (tid < 256) {  // fe layer 1: 8x32 neurons
    int b = tid >> 5, j = tid & 31;
    double v = (double)fe_w1[j] * sh_avg[b] + (double)fe_b1[j];
    sh_h1[b][j] = v > 0.0 ? v : 0.0;
  }
  __syncthreads();
  if (tid < 128) {  // fe layer 2: 8x16 neurons
    int b = tid >> 4, j = tid & 15;
    double acc = (double)fe_b2[j];
    for (int i = 0; i < 32; ++i) acc += (double)fe_w2[j * 32 + i] * sh_h1[b][i];
    sh_z[b][j] = acc > 0.0 ? acc : 0.0;
  }
  if (tid >= 256 && tid < 256 + Bq) {  // append [alpha,beta]
    sh_z[tid - 256][16] = alpha;
    sh_z[tid - 256][17] = beta;
  }
  __syncthreads();
  {  // pr layer 1: 8x64 neurons (all 512 threads)
    int b = tid >> 6, j = tid & 63;
    double acc = (double)pr_b1[j];
    for (int i = 0; i < 18; ++i) acc += (double)pr_w1[j * 18 + i] * sh_z[b][i];
    sh_z1[b][j] = acc > 0.0 ? acc : 0.0;
  }
  __syncthreads();
  if (tid < 256) {  // pr layer 2: 8x32 neurons
    int b = tid >> 5, j = tid & 31;
    double acc = (double)pr_b2[j];
    for (int i = 0; i < 64; ++i) acc += (double)pr_w2[j * 64 + i] * sh_z1[b][i];
    sh_z2[b][j] = acc > 0.0 ? acc : 0.0;
  }
  __syncthreads();
  if (tid < 16) {  // pr layer 3: 8x2 neurons + tanh*fac*0.1
    int b = tid >> 1, c = tid & 1;
    double acc = (double)pr_b3[c];
    for (int i = 0; i < 32; ++i) acc += (double)pr_w3[c * 32 + i] * sh_z2[b][i];
    double fac = 1.0 / (1.0 + exp(-(double)iter_w_p[0] * iter));
    sh_res[b][c] = tanh(acc) * fac * 0.1;
  }
  __syncthreads();
  if (tid == 0) {
    double r0 = 0.0, r1 = 0.0;
    for (int b = 0; b < Bq; ++b) { r0 += sh_res[b][0]; r1 += sh_res[b][1]; }
    double na = alpha + r0 * alpha * (1.0 / Bq);
    na = fmin(fmax(na, 1e-6), 0.01);
    double nb = beta + r1 * beta * (1.0 / Bq);
    nb = fmin(fmax(nb, 1e-6), 0.1);
    double betathr = fmin(pow(10.0, iter / 36.0 - 10.0), nb);
    hdr[0] = na;
    hdr[1] = nb;
    hdr[2] = 2.0 / na;       // coefA
    hdr[3] = 2.0 / betathr;  // coefS
    hdr[4] = 1.0 / na;       // inv_alpha
    out_scal[0] = (float)na;
    out_scal[1] = (float)nb;
  }
}

// ---------------- kernel B: u = projec5(...) ----------------
__global__ __launch_bounds__(TPB) void u_kernel(
    const float* __restrict__ s, const float* __restrict__ sum_x,
    const float* __restrict__ sum_y, const float* __restrict__ lamuda,
    const float* __restrict__ var_p, const double* __restrict__ hdr,
    double* __restrict__ u_w) {
  __shared__ double sh_red[4];
  __shared__ double sh_scale;
  int bb = blockIdx.x * Nq;
  int tid = threadIdx.x;
  double inva = hdr[4];
  double t[EPT];
  double loc = 0.0;
#pragma unroll
  for (int e = 0; e < EPT; ++e) {
    int i = tid + e * TPB;
    t[e] = (double)s[bb + i] - (double)sum_x[bb + i] - (double)sum_y[bb + i] -
           (double)lamuda[bb + i] * inva;
    loc += t[e] * t[e];
  }
  double nsq = blk_reduce(loc, sh_red);
  if (tid == 0) {
    double n = sqrt(nsq);
    double ee = sqrt((double)Nq * (double)var_p[0]);
    sh_scale = (n > ee) ? ee / fmax(n, 1e-30) : 1.0;
  }
  __syncthreads();
  double scale = sh_scale;
#pragma unroll
  for (int e = 0; e < EPT; ++e) u_w[bb + tid + e * TPB] = t[e] * scale;
}

// ---------------- kernel C: cumtrapz scan + rhs ----------------
__global__ __launch_bounds__(TPB) void phase_rhs_kernel(
    const float* __restrict__ s, const float* __restrict__ eIF,
    const float* __restrict__ xm, const float* __restrict__ ym,
    const float* __restrict__ sum_x, const float* __restrict__ sum_y,
    const float* __restrict__ lamuda, const float* __restrict__ fs_p,
    const double* __restrict__ hdr, const double* __restrict__ u_w,
    double* __restrict__ cos_w, double* __restrict__ sin_w,
    double* __restrict__ rhsx_w, double* __restrict__ rhsy_w) {
  __shared__ double sh[TPB];
  __shared__ double sh_y0;
  int row = blockIdx.x;
  int bb = (row >> 2) * Nq;  // K=4
  int base = row * Nq;
  int tid = threadIdx.x;
  int i0 = tid * EPT;
  double e[EPT], l[EPT];
#pragma unroll
  for (int j = 0; j < EPT; ++j) e[j] = (double)eIF[base + i0 + j];
  l[0] = e[0];
#pragma unroll
  for (int j = 1; j < EPT; ++j) l[j] = l[j - 1] + e[j];
  if (tid == 0) sh_y0 = e[0];
  sh[tid] = l[EPT - 1];
  __syncthreads();
  for (int off = 1; off < TPB; off <<= 1) {
    double t = (tid >= off) ? sh[tid - off] : 0.0;
    __syncthreads();
    if (tid >= off) sh[tid] += t;
    __syncthreads();
  }
  double offs = sh[tid] - l[EPT - 1];  // exclusive prefix
  double y0 = sh_y0;
  double dx = 1.0 / (double)fs_p[0];
  double inva = hdr[4];
  double c0 = PI_D * dx;
#pragma unroll
  for (int j = 0; j < EPT; ++j) {
    int i = i0 + j;
    double S = offs + l[j];
    double ph = c0 * (2.0 * S - e[j] - y0);  // == 2*pi*cumtrapz
    double sv, cv;
    sincos(ph, &sv, &cv);
    double xmv = (double)xm[base + i], ymv = (double)ym[base + i];
    double resid = (double)s[bb + i] - ((double)sum_x[bb + i] - xmv * cv) -
                   ((double)sum_y[bb + i] - ymv * sv) - u_w[bb + i] -
                   (double)lamuda[bb + i] * inva;
    cos_w[base + i] = cv;
    sin_w[base + i] = sv;
    rhsx_w[base + i] = cv * resid;
    rhsy_w[base + i] = sv * resid;
  }
}

// ---------------- kernel D: CG for xs (blocks 0..31) and ys (32..63) ----------
__global__ __launch_bounds__(TPB) void cg_xy_kernel(
    const double* __restrict__ cos_w, const double* __restrict__ sin_w,
    const double* __restrict__ rhsx_w, const double* __restrict__ rhsy_w,
    const float* __restrict__ xm, const float* __restrict__ ym,
    const double* __restrict__ hdr, double* __restrict__ xs_w,
    double* __restrict__ ys_w) {
  __shared__ double sh_p[Nq];
  __shared__ double sh_red[4];
  int id = blockIdx.x;
  int base = (id & 31) * Nq;
  bool isY = id >= 32;
  double coef = hdr[2];
  const double* trig = isY ? sin_w : cos_w;
  const double* rh = isY ? rhsy_w : rhsx_w;
  const float* x0f = isY ? ym : xm;
  int tid = threadIdx.x;
  double diagv[EPT], r[EPT], x[EPT];
#pragma unroll
  for (int e = 0; e < EPT; ++e) {
    int i = base + tid + e * TPB;
    double t = trig[i];
    diagv[e] = t * t;
    r[e] = rh[i];
    x[e] = (double)x0f[i];
  }
  cg_block(coef, diagv, r, x, sh_p, sh_red);
  double* outw = isY ? ys_w : xs_w;
#pragma unroll
  for (int e = 0; e < EPT; ++e) outw[base + tid + e * TPB] = x[e];
}

// ---------------- kernel F: fused deltaIF + smooth CG + eIF/xm/ym outputs ----
__global__ __launch_bounds__(TPB) void cg_smooth_kernel(
    const double* __restrict__ hdr, const float* __restrict__ eIF,
    const double* __restrict__ xs_w, const double* __restrict__ ys_w,
    const float* __restrict__ xm, const float* __restrict__ ym,
    const int* __restrict__ mode_mask, const float* __restrict__ fs_p,
    double* __restrict__ eifn_w, float* __restrict__ out_eIF,
    float* __restrict__ out_xm, float* __restrict__ out_ym) {
  __shared__ double sh_p[Nq];
  __shared__ double sh_red[4];
  int row = blockIdx.x;
  int base = row * Nq;
  int tid = threadIdx.x;
  double fsv = (double)fs_p[0];
  double invdx = fsv, inv2dx = 0.5 * fsv;

  // deltaIF via LDS staging (replaces dif_kernel)
  double xv[EPT], xb[EPT];
#pragma unroll
  for (int e = 0; e < EPT; ++e) sh_p[tid + e * TPB] = xs_w[base + tid + e * TPB];
  __syncthreads();
#pragma unroll
  for (int e = 0; e < EPT; ++e) {
    int i = tid + e * TPB;
    xv[e] = sh_p[i];
    if (i == 0) xb[e] = (sh_p[1] - sh_p[0]) * invdx;
    else if (i == Nq - 1) xb[e] = (sh_p[Nq - 1] - sh_p[Nq - 2]) * invdx;
    else xb[e] = (sh_p[i + 1] - sh_p[i - 1]) * inv2dx;
  }
  __syncthreads();
#pragma unroll
  for (int e = 0; e < EPT; ++e) sh_p[tid + e * TPB] = ys_w[base + tid + e * TPB];
  __syncthreads();
  double diagv[EPT], r[EPT], x[EPT];
#pragma unroll
  for (int e = 0; e < EPT; ++e) {
    int i = tid + e * TPB;
    double yv = sh_p[i];
    double yb;
    if (i == 0) yb = (sh_p[1] - sh_p[0]) * invdx;
    else if (i == Nq - 1) yb = (sh_p[Nq - 1] - sh_p[Nq - 2]) * invdx;
    else yb = (sh_p[i + 1] - sh_p[i - 1]) * inv2dx;
    double denom = xv[e] * xv[e] + yv * yv + 1e-12;
    r[e] = (xv[e] * yb - yv * xb[e]) / (denom * TWO_PI_D);
    diagv[e] = 1.0;
    x[e] = 0.0;
  }
  __syncthreads();  // all ys reads done before cg_block overwrites sh_p

  cg_block(hdr[3], diagv, r, x, sh_p, sh_red);

  bool active = mode_mask[row] != 0;
#pragma unroll
  for (int e = 0; e < EPT; ++e) {
    int i = base + tid + e * TPB;
    double eifv = (double)eIF[i];
    double ne = active ? (eifv - 0.5 * x[e]) : eifv;
    eifn_w[i] = ne;
    out_eIF[i] = (float)ne;
    out_xm[i] = active ? (float)xs_w[i] : xm[i];
    out_ym[i] = active ? (float)ys_w[i] : ym[i];
  }
}

// ---------------- kernel G: new_phase scan + masked contributions -----------
__global__ __launch_bounds__(TPB) void phase2_kernel(
    const double* __restrict__ eifn_w, const double* __restrict__ xs_w,
    const double* __restrict__ ys_w, const int* __restrict__ mode_mask,
    const float* __restrict__ fs_p, double* __restrict__ cx_w,
    double* __restrict__ cy_w) {
  __shared__ double sh[TPB];
  __shared__ double sh_y0;
  int row = blockIdx.x;
  int base = row * Nq;
  int tid = threadIdx.x;
  int i0 = tid * EPT;
  double e[EPT], l[EPT];
#pragma unroll
  for (int j = 0; j < EPT; ++j) e[j] = eifn_w[base + i0 + j];
  l[0] = e[0];
#pragma unroll
  for (int j = 1; j < EPT; ++j) l[j] = l[j - 1] + e[j];
  if (tid == 0) sh_y0 = e[0];
  sh[tid] = l[EPT - 1];
  __syncthreads();
  for (int off = 1; off < TPB; off <<= 1) {
    double t = (tid >= off) ? sh[tid - off] : 0.0;
    __syncthreads();
    if (tid >= off) sh[tid] += t;
    __syncthreads();
  }
  double offs = sh[tid] - l[EPT - 1];
  double y0 = sh_y0;
  double dx = 1.0 / (double)fs_p[0];
  double c0 = PI_D * dx;
  bool active = mode_mask[row] != 0;
#pragma unroll
  for (int j = 0; j < EPT; ++j) {
    int i = i0 + j;
    double S = offs + l[j];
    double ph = c0 * (2.0 * S - e[j] - y0);
    double sv, cv;
    sincos(ph, &sv, &cv);
    if (active) {
      cx_w[base + i] = xs_w[base + i] * cv;
      cy_w[base + i] = ys_w[base + i] * sv;
    } else {
      cx_w[base + i] = 0.0;
      cy_w[base + i] = 0.0;
    }
  }
}

// ---------------- kernel H: bsx/bsy sums + new lamuda ----------------
__global__ __launch_bounds__(TPB) void final_kernel(
    const float* __restrict__ s, const float* __restrict__ lamuda,
    const double* __restrict__ u_w, const double* __restrict__ cx_w,
    const double* __restrict__ cy_w, const double* __restrict__ hdr,
    float* __restrict__ out_bsx, float* __restrict__ out_bsy,
    float* __restrict__ out_lam) {
  int b = blockIdx.x;
  int bb = b * Nq;
  int tid = threadIdx.x;
  double na = hdr[0];
#pragma unroll
  for (int e = 0; e < EPT; ++e) {
    int i = tid + e * TPB;
    int gi = bb + i;
    double bx = 0.0, by = 0.0;
#pragma unroll
    for (int k = 0; k < Kq; ++k) {
      bx += cx_w[(b * Kq + k) * Nq + i];
      by += cy_w[(b * Kq + k) * Nq + i];
    }
    double nl = (double)lamuda[gi] + na * (u_w[gi] + bx + by - (double)s[gi]);
    out_bsx[gi] = (float)bx;
    out_bsy[gi] = (float)by;
    out_lam[gi] = (float)nl;
  }
}

// ---------------- launcher ----------------
extern "C" void kernel_launch(void* const* d_in, const int* in_sizes, int n_in,
                              void* d_out, int out_size, void* d_ws, size_t ws_size,
                              hipStream_t stream) {
  (void)in_sizes; (void)n_in; (void)out_size; (void)ws_size;
  const float* s = (const float*)d_in[0];
  const float* eIF = (const float*)d_in[1];
  const float* xm = (const float*)d_in[2];
  const float* ym = (const float*)d_in[3];
  const float* sum_x = (const float*)d_in[4];
  const float* sum_y = (const float*)d_in[5];
  const float* lamuda = (const float*)d_in[6];
  const float* init_freqs = (const float*)d_in[7];
  const int* mode_mask = (const int*)d_in[8];
  const float* alpha = (const float*)d_in[9];
  const float* beta = (const float*)d_in[10];
  const float* var = (const float*)d_in[11];
  const float* fs = (const float*)d_in[12];
  const int* iteration = (const int*)d_in[13];
  const float* fe_w1 = (const float*)d_in[14];
  const float* fe_b1 = (const float*)d_in[15];
  const float* fe_w2 = (const float*)d_in[16];
  const float* fe_b2 = (const float*)d_in[17];
  const float* pr_w1 = (const float*)d_in[18];
  const float* pr_b1 = (const float*)d_in[19];
  const float* pr_w2 = (const float*)d_in[20];
  const float* pr_b2 = (const float*)d_in[21];
  const float* pr_w3 = (const float*)d_in[22];
  const float* pr_b3 = (const float*)d_in[23];
  const float* iter_weight = (const float*)d_in[24];

  float* out = (float*)d_out;
  const int BN = Bq * Nq;      // 16384
  const int BKN = BKq * Nq;    // 65536
  float* out_eIF = out;
  float* out_xm = out + BKN;
  float* out_ym = out + 2 * BKN;
  float* out_bsx = out + 3 * BKN;
  float* out_bsy = out + 3 * BKN + BN;
  float* out_lam = out + 3 * BKN + 2 * BN;
  float* out_scal = out + 3 * BKN + 3 * BN;  // [new_alpha, new_beta]

  double* W = (double*)d_ws;
  double* hdr = W;            // 16
  double* u_w = W + 16;       // BN
  double* cos_w = u_w + BN;   // BKN each below
  double* sin_w = cos_w + BKN;
  double* rhsx_w = sin_w + BKN;
  double* rhsy_w = rhsx_w + BKN;
  double* xs_w = rhsy_w + BKN;
  double* ys_w = xs_w + BKN;
  double* eifn_w = ys_w + BKN;
  double* cx_w = eifn_w + BKN;
  double* cy_w = cx_w + BKN;   // total ~4.9 MB

  hyper_kernel<<<1, 512, 0, stream>>>(init_freqs, alpha, beta, iteration, fe_w1,
                                      fe_b1, fe_w2, fe_b2, pr_w1, pr_b1, pr_w2,
                                      pr_b2, pr_w3, pr_b3, iter_weight, hdr,
                                      out_scal);
  u_kernel<<<Bq, TPB, 0, stream>>>(s, sum_x, sum_y, lamuda, var, hdr, u_w);
  phase_rhs_kernel<<<BKq, TPB, 0, stream>>>(s, eIF, xm, ym, sum_x, sum_y, lamuda,
                                            fs, hdr, u_w, cos_w, sin_w, rhsx_w,
                                            rhsy_w);
  cg_xy_kernel<<<2 * BKq, TPB, 0, stream>>>(cos_w, sin_w, rhsx_w, rhsy_w, xm, ym,
                                            hdr, xs_w, ys_w);
  cg_smooth_kernel<<<BKq, TPB, 0, stream>>>(hdr, eIF, xs_w, ys_w, xm, ym,
                                            mode_mask, fs, eifn_w, out_eIF,
                                            out_xm, out_ym);
  phase2_kernel<<<BKq, TPB, 0, stream>>>(eifn_w, xs_w, ys_w, mode_mask, fs, cx_w,
                                         cy_w);
  final_kernel<<<Bq, TPB, 0, stream>>>(s, lamuda, u_w, cx_w, cy_w, hdr, out_bsx,
                                       out_bsy, out_lam);
}